// Round 3
// baseline (303.127 us; speedup 1.0000x reference)
//
#include <hip/hip_runtime.h>
#include <stdint.h>

#define BTOT 32768
#define NIMG 16      // images per conv block
#define KF   416     // padded feature dim (400 real)

typedef __attribute__((ext_vector_type(8))) short short8;
typedef __attribute__((ext_vector_type(4))) float floatx4;
typedef __attribute__((ext_vector_type(4))) unsigned int uintx4;

__device__ __forceinline__ unsigned short f2bf(float x) {
    union { float f; unsigned int u; } v; v.f = x;
    unsigned int r = v.u + 0x7fffu + ((v.u >> 16) & 1u);  // RNE
    return (unsigned short)(r >> 16);
}

// ---------------- conv(5x5,3->16) + bias + relu + 2x2 maxpool via MFMA implicit GEMM ----------
// M = positions (m = quad*4 + corner -> in-lane 2x2 pool in D), N = 16 co.
// K chunks = (ci,row): taps row*5..row*5+4 (+3 zero slots); 15 real + 1 dead chunk = 4 K=32 MFMAs.
// This rev: fully-unrolled 25-tile loop with nxt[12] register prefetch (tile t+1's LDS reads
// issue under tile t's MFMAs), incremental mod-25 index walk, and DIRECT global u16 stores
// (s_out LDS staging deleted -- 3.3 KB/wave output is L2-resident; saves 13.3 KB LDS + barrier).
__global__ __launch_bounds__(256) void conv_pool_kernel(
    const float* __restrict__ fm, const float* __restrict__ cw,
    const float* __restrict__ cb, unsigned short* __restrict__ feat,
    const float* __restrict__ lw, unsigned short* __restrict__ Wb)
{
    // -------- folded prep_w path (blocks 2048..2255) --------
    if (blockIdx.x >= BTOT / NIMG) {
        int c = (blockIdx.x - BTOT / NIMG) * 256 + threadIdx.x;   // one 8-element chunk
        if (c < 1024 * 52) {
            int n = c / 52;
            int kc = (c - n * 52) * 8;
            unsigned short v[8];
            #pragma unroll
            for (int j = 0; j < 8; ++j) {
                int k = kc + j;
                float x = (n < 1000 && k < 400) ? lw[n * 400 + k] : 0.f;
                v[j] = f2bf(x);
            }
            *(uint4*)(Wb + (size_t)n * KF + kc) = *(uint4*)v;
        }
        return;
    }

    __shared__ __align__(16) unsigned short s_img[NIMG * 588];   // bf16 images, 18816 B

    const int tid  = threadIdx.x;
    const int b0   = blockIdx.x * NIMG;
    const int lane = tid & 63;
    const int wave = tid >> 6;

    // stage 16 images fp32 -> bf16, b128 LDS writes
    const float4* in4 = (const float4*)(fm + (size_t)b0 * 588);
    for (int idx = tid; idx < NIMG * 147 / 2; idx += 256) {
        float4 v0 = in4[2 * idx], v1 = in4[2 * idx + 1];
        uint4 u;
        u.x = (unsigned int)f2bf(v0.x) | ((unsigned int)f2bf(v0.y) << 16);
        u.y = (unsigned int)f2bf(v0.z) | ((unsigned int)f2bf(v0.w) << 16);
        u.z = (unsigned int)f2bf(v1.x) | ((unsigned int)f2bf(v1.y) << 16);
        u.w = (unsigned int)f2bf(v1.z) | ((unsigned int)f2bf(v1.w) << 16);
        *(uint4*)&s_img[idx * 8] = u;
    }

    const int co = lane & 15;       // B col / D col
    const int q  = lane >> 4;       // k-chunk select (A/B), quad-in-tile (D)
    const int r  = lane & 15;       // A row (M within tile)
    const int qd = r >> 2;          // quad within tile
    const int cy = (r >> 1) & 1;    // pool corner y
    const int cx = r & 1;           // pool corner x
    const int sh = cx << 4;         // alignbit shift for odd column start

    // weights per chunk c = 4i+q: (ci,row) = (c/5, c%5) for c<15; c==15 dead (all-zero)
    short8 bw[4];
    int cdw[4];                     // dword offset of chunk row within image: ci*98 + row*7
    #pragma unroll
    for (int i = 0; i < 4; ++i) {
        int c = 4 * i + q;
        int ci = (c < 15) ? (c / 5) : 0;
        int row = (c < 15) ? (c - ci * 5) : 0;
        cdw[i] = ci * 98 + row * 7;
        #pragma unroll
        for (int j = 0; j < 8; ++j)
            bw[i][j] = (c < 15 && j < 5) ? (short)f2bf(cw[co * 75 + ci * 25 + row * 5 + j])
                                         : (short)0;
    }
    const float bias = cb[co];

    __syncthreads();

    const unsigned int* sw32 = (const unsigned int*)s_img + wave * 1176;  // 4 images/wave
    unsigned short* fb = feat + (size_t)(b0 + wave * 4) * KF + co * 25;

    int imga = 0, q25a = qd;        // A-gather walk (g = t*4 + qd)
    int imgs = 0, q25s = q;         // store walk    (gd = t*4 + q)

    unsigned int cur[12], nxt[12];

    {   // prologue: loads for t = 0
        int qy = (q25a * 13) >> 6, qx = q25a - qy * 5;
        const unsigned int* p = sw32 + imga * 294 + (qy * 2 + cy) * 7 + qx;
        #pragma unroll
        for (int i = 0; i < 4; ++i) {
            cur[3 * i] = p[cdw[i]]; cur[3 * i + 1] = p[cdw[i] + 1]; cur[3 * i + 2] = p[cdw[i] + 2];
        }
    }

    #pragma unroll
    for (int t = 0; t < 25; ++t) {
        if (t < 24) {               // prefetch tile t+1 before consuming tile t
            q25a += 4; if (q25a >= 25) { q25a -= 25; imga += 1; }
            int qy = (q25a * 13) >> 6, qx = q25a - qy * 5;
            const unsigned int* p = sw32 + imga * 294 + (qy * 2 + cy) * 7 + qx;
            #pragma unroll
            for (int i = 0; i < 4; ++i) {
                nxt[3 * i] = p[cdw[i]]; nxt[3 * i + 1] = p[cdw[i] + 1]; nxt[3 * i + 2] = p[cdw[i] + 2];
            }
        }
        floatx4 acc = {0.f, 0.f, 0.f, 0.f};
        #pragma unroll
        for (int i = 0; i < 4; ++i) {
            uintx4 a;
            a.x = __builtin_amdgcn_alignbit(cur[3 * i + 1], cur[3 * i + 0], sh); // taps c0,c1
            a.y = __builtin_amdgcn_alignbit(cur[3 * i + 2], cur[3 * i + 1], sh); // taps c2,c3
            a.z = __builtin_amdgcn_alignbit(cur[3 * i + 2], cur[3 * i + 2], sh); // tap c4 (+dead)
            a.w = 0u;                                                            // slots 6,7 dead
            acc = __builtin_amdgcn_mfma_f32_16x16x32_bf16(
                __builtin_bit_cast(short8, a), bw[i], acc, 0, 0, 0);
        }
        // D: lane holds quad (lane>>4) corners in acc[0..3], col = co -> in-lane 2x2 pool
        float m = fmaxf(fmaxf(acc[0], acc[1]), fmaxf(acc[2], acc[3])) + bias;
        fb[imgs * 416 + q25s] = f2bf(fmaxf(m, 0.f));   // direct global u16, L2 combines
        if (t < 24) {
            q25s += 4; if (q25s >= 25) { q25s -= 25; imgs += 1; }
            #pragma unroll
            for (int k = 0; k < 12; ++k) cur[k] = nxt[k];   // SSA-renamed, no real movs
        }
    }

    // zero-pad feat[b][400..416) for this wave's 4 images
    if (lane < 16) {
        int img = lane >> 2, k = lane & 3;
        *(uint2*)(feat + (size_t)(b0 + wave * 4 + img) * KF + 400 + k * 4) = make_uint2(0u, 0u);
    }
}

// ---------------- GEMM: out[32768][1000] = F[32768][416] @ Wb[1024][416]^T + lin_b ----------------
// m97 pattern: global_load_lds width=16 staging (dest = wave-uniform base + lane*16).
__global__ __launch_bounds__(256) void gemm_kernel(
    const unsigned short* __restrict__ F, const unsigned short* __restrict__ Wb,
    const float* __restrict__ lb, float* __restrict__ out)
{
    __shared__ __align__(16) unsigned short At[128 * 32];
    __shared__ __align__(16) unsigned short Bt[128 * 32];

    const int tid = threadIdx.x;
    const int bm = blockIdx.x >> 3;
    const int bn = blockIdx.x & 7;
    const int m0 = bm * 128;
    const int n0 = bn * 128;

    const int w = tid >> 6;
    const int lane = tid & 63;
    const int wm = w & 1, wn = w >> 1;     // 2x2 wave grid, each wave 64x64
    const int lq = lane >> 4, ln = lane & 15;

    floatx4 zero = {0.f, 0.f, 0.f, 0.f};
    floatx4 acc[4][4];
    #pragma unroll
    for (int i = 0; i < 4; ++i)
        #pragma unroll
        for (int j = 0; j < 4; ++j) acc[i][j] = zero;

    // staging: wave w covers rows [w*16, w*16+16) (+64 for t=1); lane L -> row w*16+(L>>2), chunk L&3
    const int srow = w * 16 + (lane >> 2);
    const int skc = (lane & 3) * 8;
    const unsigned short* gA = F + (size_t)(m0 + srow) * KF + skc;
    const unsigned short* gB = Wb + (size_t)(n0 + srow) * KF + skc;

    for (int kb = 0; kb < KF; kb += 32) {
        #pragma unroll
        for (int t = 0; t < 2; ++t) {
            __builtin_amdgcn_global_load_lds(
                (const __attribute__((address_space(1))) void*)(gA + (size_t)(t * 64) * KF + kb),
                (__attribute__((address_space(3))) void*)&At[(w * 16 + t * 64) * 32],
                16, 0, 0);
            __builtin_amdgcn_global_load_lds(
                (const __attribute__((address_space(1))) void*)(gB + (size_t)(t * 64) * KF + kb),
                (__attribute__((address_space(3))) void*)&Bt[(w * 16 + t * 64) * 32],
                16, 0, 0);
        }
        __syncthreads();
        short8 af[4], bf[4];
        #pragma unroll
        for (int i = 0; i < 4; ++i)
            af[i] = *(const short8*)&At[(wm * 64 + i * 16 + ln) * 32 + lq * 8];
        #pragma unroll
        for (int j = 0; j < 4; ++j)
            bf[j] = *(const short8*)&Bt[(wn * 64 + j * 16 + ln) * 32 + lq * 8];
        #pragma unroll
        for (int i = 0; i < 4; ++i)
            #pragma unroll
            for (int j = 0; j < 4; ++j)
                acc[i][j] = __builtin_amdgcn_mfma_f32_16x16x32_bf16(af[i], bf[j], acc[i][j], 0, 0, 0);
        __syncthreads();
    }

    #pragma unroll
    for (int j = 0; j < 4; ++j) {
        int n = n0 + wn * 64 + j * 16 + ln;
        if (n >= 1000) continue;           // padded N region
        float bias = lb[n];
        #pragma unroll
        for (int i = 0; i < 4; ++i) {
            int mb = m0 + wm * 64 + i * 16 + lq * 4;   // C/D: col=lane&15, row=quad*4+reg (m89/m91)
            #pragma unroll
            for (int rr = 0; rr < 4; ++rr)
                out[(size_t)(mb + rr) * 1000 + n] = acc[i][j][rr] + bias;
        }
    }
}

extern "C" void kernel_launch(void* const* d_in, const int* in_sizes, int n_in,
                              void* d_out, int out_size, void* d_ws, size_t ws_size,
                              hipStream_t stream)
{
    const float* fm = (const float*)d_in[0];   // (32768,3,14,14)
    const float* cw = (const float*)d_in[1];   // (16,3,5,5)
    const float* cb = (const float*)d_in[2];   // (16,)
    const float* lw = (const float*)d_in[3];   // (1000,400)
    const float* lb = (const float*)d_in[4];   // (1000,)
    float* out = (float*)d_out;                // (32768,1000) fp32

    unsigned short* feat = (unsigned short*)d_ws;                        // [32768][416] bf16
    unsigned short* Wb   = (unsigned short*)d_ws + (size_t)BTOT * KF;    // [1024][416] bf16

    // conv blocks [0,2048) + folded prep_w blocks [2048,2256)
    conv_pool_kernel<<<BTOT / NIMG + 208, 256, 0, stream>>>(fm, cw, cb, feat, lw, Wb);
    gemm_kernel<<<2048, 256, 0, stream>>>(feat, Wb, lb, out);
}